// Round 8
// baseline (340.390 us; speedup 1.0000x reference)
//
#include <hip/hip_runtime.h>
#include <cstdint>
#include <cstddef>

// Problem constants
#define BB      2
#define TT      2048
#define WID     1024
#define NH      16
#define HD      64
#define WIN     1024
#define MROWS   (BB*TT)      // 4096
#define NQKV    1152         // 1024 q + 64 k + 64 v
#define QSCL    0.18033688011112042f   // (1/8) * log2(e)  -> exp2-domain logits

typedef __attribute__((ext_vector_type(8))) short  short8;   // 8 bf16 in 4 VGPRs
typedef __attribute__((ext_vector_type(4))) float  floatx4;  // MFMA accumulator

__device__ __forceinline__ unsigned short f2bf(float f) {
  union { float f; unsigned int u; } v; v.f = f;
  unsigned int u = v.u;
  unsigned int r = (u + 0x7fffu + ((u >> 16) & 1u)) >> 16;  // RNE
  return (unsigned short)r;
}

__device__ __forceinline__ float fast_exp2(float x) {
#if __has_builtin(__builtin_amdgcn_exp2f)
  return __builtin_amdgcn_exp2f(x);
#else
  return exp2f(x);
#endif
}

// pack two fp32 -> two bf16 (truncation) in one v_perm_b32
__device__ __forceinline__ unsigned int pk_bf16_trunc(float lo, float hi) {
  union { float f; unsigned int u; } a, b; a.f = lo; b.f = hi;
#if __has_builtin(__builtin_amdgcn_perm)
  return __builtin_amdgcn_perm(b.u, a.u, 0x07060302u);
#else
  return (b.u & 0xffff0000u) | (a.u >> 16);
#endif
}

// async global->LDS, 16B per lane; lds ptr must be wave-uniform (HW adds lane*16)
__device__ __forceinline__ void gld_lds16(const void* g, void* l) {
  __builtin_amdgcn_global_load_lds(
      (const __attribute__((address_space(1))) unsigned int*)g,
      (__attribute__((address_space(3))) unsigned int*)l, 16, 0, 0);
}

// ---------------------------------------------------------------------------
// Kernel 1: fp32 -> bf16 conversion for x, packed W=[Wq;Wk;Wv], Wf
// ---------------------------------------------------------------------------
__global__ __launch_bounds__(256) void convert_kernel(
    const float* __restrict__ x,  const float* __restrict__ wq,
    const float* __restrict__ wk, const float* __restrict__ wv,
    const float* __restrict__ wf,
    unsigned short* __restrict__ xb, unsigned short* __restrict__ wb,
    unsigned short* __restrict__ wfb)
{
  const int NX4 = (MROWS * WID) / 4;
  const int NQ4 = (WID * WID) / 4;
  const int NK4 = (HD * WID) / 4;
  const int NW4 = NQ4 + 2 * NK4;
  const int NF4 = (WID * WID) / 4;
  const int TOT = NX4 + NW4 + NF4;
  for (int i = blockIdx.x * blockDim.x + threadIdx.x; i < TOT;
       i += gridDim.x * blockDim.x) {
    float4 v4;
    unsigned short* dptr;
    if (i < NX4) {
      v4 = ((const float4*)x)[i];
      dptr = xb + (size_t)i * 4;
    } else if (i < NX4 + NW4) {
      int k = i - NX4;
      dptr = wb + (size_t)k * 4;
      if (k < NQ4)            v4 = ((const float4*)wq)[k];
      else if (k < NQ4 + NK4) v4 = ((const float4*)wk)[k - NQ4];
      else                    v4 = ((const float4*)wv)[k - NQ4 - NK4];
    } else {
      int k = i - NX4 - NW4;
      v4 = ((const float4*)wf)[k];
      dptr = wfb + (size_t)k * 4;
    }
    ushort4 o4 = make_ushort4(f2bf(v4.x), f2bf(v4.y), f2bf(v4.z), f2bf(v4.w));
    *(ushort4*)dptr = o4;
  }
}

// ---------------------------------------------------------------------------
// Kernel 2: bf16 MFMA GEMM, C(MxN) = A(MxK) * B(NxK)^T.   (frozen from R6)
// BM=64, BN=128, BK=64, 256 threads = 4 waves (2x2), wave = 32x64 out,
// 16 MFMA per wave per barrier; double-buffered LDS, ONE barrier per K-iter.
// global_load_lds staging with chunk swizzle (c+row)&7; reader de-swizzles
// with slot (j - m)&7.
// mode 0: C f32 + bias.  mode 1: split bf16 epilogue -> qb (scaled), kb, vtb.
// ---------------------------------------------------------------------------
__global__ __launch_bounds__(256) void gemm64(
    const unsigned short* __restrict__ A, const unsigned short* __restrict__ Bm,
    int M, int N, int K, int mode,
    float* __restrict__ C, const float* __restrict__ bias,
    unsigned short* __restrict__ qb, unsigned short* __restrict__ kb,
    unsigned short* __restrict__ vtb)
{
  __shared__ __align__(16) unsigned short As[2][64 * 64];    // 2 x 8 KB
  __shared__ __align__(16) unsigned short Bs[2][128 * 64];   // 2 x 16 KB

  const int tid  = threadIdx.x;
  const int m0   = blockIdx.x * 64;
  const int n0   = blockIdx.y * 128;
  const int w    = tid >> 6;
  const int lane = tid & 63;
  const int wr   = w >> 1;        // 0..1 -> 32-row slab
  const int wc   = w & 1;         // 0..1 -> 64-col slab
  const int quad = lane >> 4;
  const int l16  = lane & 15;

  const int rS  = tid >> 3;             // 0..31
  const int cS  = tid & 7;
  const int csS = (cS + rS) & 7;
  const unsigned short* gA0 = A  + (size_t)(m0 + rS) * K + csS * 8;
  const unsigned short* gA1 = gA0 + (size_t)32 * K;
  const unsigned short* gB0 = Bm + (size_t)(n0 + rS) * K + csS * 8;
  const unsigned short* gB1 = gB0 + (size_t)32 * K;
  const unsigned short* gB2 = gB0 + (size_t)64 * K;
  const unsigned short* gB3 = gB0 + (size_t)96 * K;
  const int wub = (tid & 192) * 16;     // wave-uniform byte base within round

  floatx4 acc[2][4];
#pragma unroll
  for (int it = 0; it < 2; ++it)
#pragma unroll
    for (int jt = 0; jt < 4; ++jt)
      acc[it][jt] = (floatx4){0.f, 0.f, 0.f, 0.f};

  const int K64 = K >> 6;
  gld_lds16(gA0, (char*)As[0] + wub);
  gld_lds16(gA1, (char*)As[0] + 4096 + wub);
  gld_lds16(gB0, (char*)Bs[0] + wub);
  gld_lds16(gB1, (char*)Bs[0] + 4096 + wub);
  gld_lds16(gB2, (char*)Bs[0] + 8192 + wub);
  gld_lds16(gB3, (char*)Bs[0] + 12288 + wub);
  __syncthreads();

  for (int kt = 0; kt < K64; ++kt) {
    const int cur = kt & 1;
    if (kt + 1 < K64) {
      const int nxt = cur ^ 1;
      const int off = (kt + 1) * 64;
      gld_lds16(gA0 + off, (char*)As[nxt] + wub);
      gld_lds16(gA1 + off, (char*)As[nxt] + 4096 + wub);
      gld_lds16(gB0 + off, (char*)Bs[nxt] + wub);
      gld_lds16(gB1 + off, (char*)Bs[nxt] + 4096 + wub);
      gld_lds16(gB2 + off, (char*)Bs[nxt] + 8192 + wub);
      gld_lds16(gB3 + off, (char*)Bs[nxt] + 12288 + wub);
    }
    const unsigned short* as = As[cur];
    const unsigned short* bs = Bs[cur];
    short8 af[2][2], bfr[4][2];
#pragma unroll
    for (int it = 0; it < 2; ++it) {
      const int m = wr * 32 + it * 16 + l16;
#pragma unroll
      for (int ks = 0; ks < 2; ++ks)
        af[it][ks] = *(const short8*)(as + m * 64 + (((ks * 4 + quad) - m) & 7) * 8);
    }
#pragma unroll
    for (int jt = 0; jt < 4; ++jt) {
      const int n = wc * 64 + jt * 16 + l16;
#pragma unroll
      for (int ks = 0; ks < 2; ++ks)
        bfr[jt][ks] = *(const short8*)(bs + n * 64 + (((ks * 4 + quad) - n) & 7) * 8);
    }
#pragma unroll
    for (int ks = 0; ks < 2; ++ks)
#pragma unroll
      for (int it = 0; it < 2; ++it)
#pragma unroll
        for (int jt = 0; jt < 4; ++jt)
          acc[it][jt] = __builtin_amdgcn_mfma_f32_16x16x32_bf16(
              af[it][ks], bfr[jt][ks], acc[it][jt], 0, 0, 0);
    __syncthreads();
  }

  if (mode == 0) {
#pragma unroll
    for (int it = 0; it < 2; ++it) {
      const int gr = m0 + wr * 32 + it * 16 + quad * 4;
#pragma unroll
      for (int jt = 0; jt < 4; ++jt) {
        const int gc = n0 + wc * 64 + jt * 16 + l16;
        const float badd = bias[gc];
#pragma unroll
        for (int r = 0; r < 4; ++r)
          C[(size_t)(gr + r) * N + gc] = acc[it][jt][r] + badd;
      }
    }
  } else {
#pragma unroll
    for (int it = 0; it < 2; ++it) {
      const int gr = m0 + wr * 32 + it * 16 + quad * 4;
#pragma unroll
      for (int jt = 0; jt < 4; ++jt) {
        const int gc = n0 + wc * 64 + jt * 16 + l16;
        if (gc < WID) {                       // Q columns: scaled bf16
#pragma unroll
          for (int r = 0; r < 4; ++r)
            qb[(size_t)(gr + r) * WID + gc] = f2bf(acc[it][jt][r] * QSCL);
        } else if (gc < WID + HD) {           // K columns
#pragma unroll
          for (int r = 0; r < 4; ++r)
            kb[(size_t)(gr + r) * HD + (gc - WID)] = f2bf(acc[it][jt][r]);
        } else {                              // V columns -> vtb[hd][row]
          ushort4 o4 = make_ushort4(f2bf(acc[it][jt][0]), f2bf(acc[it][jt][1]),
                                    f2bf(acc[it][jt][2]), f2bf(acc[it][jt][3]));
          *(ushort4*)(vtb + (size_t)(gc - WID - HD) * MROWS + gr) = o4;
        }
      }
    }
  }
}

// ---------------------------------------------------------------------------
// Kernel 3: MFMA flash attention (MQA, window=1024), 4-way window split.
// Block = 1024 threads = 16 waves = 4 heads x 4 window-groups; grid (64,4,2)
// = 512 blocks -> 2 blocks/CU -> 8 waves/SIMD (launch_bounds caps VGPR=64;
// R7's identical compute body measured exactly 64).
// Per iter the block stages 128 keys of K into LDS (4 slots, one per group;
// single-buffered, register prefetch before the barrier, 2 barriers/iter —
// hidden by the co-resident block). V^T is read direct from global: its
// latency is covered by S-MFMA + softmax, unlike K which heads the chain.
// No-max softmax (fixed m=0, exp2 domain); sequential LDS merge at the end.
// LDS: Ks 4x32x80 sh (20480 B) + Ps 16x1280 sh (40960 B) = 61440 B.
// ---------------------------------------------------------------------------
__global__ __launch_bounds__(1024, 8) void attn_mfma(
    const unsigned short* __restrict__ qb, const unsigned short* __restrict__ kb,
    const unsigned short* __restrict__ vtb, unsigned short* __restrict__ attnb)
{
  __shared__ __align__(16) unsigned short smem[30720];   // 60 KB

  const int tid  = threadIdx.x;
  const int w    = tid >> 6;        // 0..15
  const int g    = w >> 2;          // window group 0..3
  const int wh   = w & 3;           // head sub-index 0..3
  const int lane = tid & 63;
  const int l16  = lane & 15;
  const int quad = lane >> 4;
  const int t0   = blockIdx.x * 32;
  const int h    = blockIdx.y * 4 + wh;
  const int b    = blockIdx.z;

  unsigned short* Psb = smem + 10240 + w * 1280;   // per-wave [query*40 + key]

  // Q B-fragments (pre-scaled bf16): lane=query l16 (+nt*16), k=quad*8+j
  short8 qf[2][2];
#pragma unroll
  for (int nt = 0; nt < 2; ++nt) {
    const unsigned short* qp =
        qb + (size_t)(b * TT + t0 + nt * 16 + l16) * WID + h * HD + quad * 8;
    qf[nt][0] = *(const short8*)qp;
    qf[nt][1] = *(const short8*)(qp + 32);
  }

  floatx4 Oacc[4][2];
#pragma unroll
  for (int mh = 0; mh < 4; ++mh)
#pragma unroll
    for (int nt = 0; nt < 2; ++nt)
      Oacc[mh][nt] = (floatx4){0.f, 0.f, 0.f, 0.f};
  float lq[2] = {0.f, 0.f};                 // per-lane partial sums

  int s_begin = t0 - WIN; if (s_begin < 0) s_begin = 0;
  const int T = ((t0 + 32) - s_begin) >> 5; // real 32-key tiles (<= 33)
  const int I = (T + 3) >> 2;               // 128-key staging rounds

  // K staging map: thread t stages key gk = t>>3, hd segment (t&7)*8
  const int gk  = tid >> 3;                 // 0..127
  const int kse = (tid & 7) * 8;
  unsigned short* KsW = smem + (gk >> 5) * 2560 + (gk & 31) * 80 + kse;
  const unsigned short* kbase = kb + (size_t)(b * TT) * HD;

  int sK = s_begin;
  int ck = sK + gk; if (ck > TT - 1) ck = TT - 1;     // OOB clamp (phantom)
  short8 kreg = *(const short8*)(kbase + (size_t)ck * HD + kse);

  for (int i = 0; i < I; ++i) {
    *(short8*)KsW = kreg;
    __syncthreads();                        // staging visible to all waves
    if (i + 1 < I) {                        // prefetch next 128-key chunk
      sK += 128;
      ck = sK + gk; if (ck > TT - 1) ck = TT - 1;
      kreg = *(const short8*)(kbase + (size_t)ck * HD + kse);
    }

    const int ta = 4 * i + g;
    if (ta < T) {                           // wave-uniform guard
      const int s0 = s_begin + ta * 32;
      const unsigned short* ks = smem + g * 2560;

      short8 kf[2][2];
#pragma unroll
      for (int mk = 0; mk < 2; ++mk)
#pragma unroll
        for (int k2 = 0; k2 < 2; ++k2)
          kf[mk][k2] = *(const short8*)(ks + (mk * 16 + l16) * 80 + k2 * 32 + quad * 8);

      floatx4 Sc[2][2];
#pragma unroll
      for (int mk = 0; mk < 2; ++mk)
#pragma unroll
        for (int nt = 0; nt < 2; ++nt)
          Sc[mk][nt] = (floatx4){0.f, 0.f, 0.f, 0.f};
#pragma unroll
      for (int mk = 0; mk < 2; ++mk)
#pragma unroll
        for (int nt = 0; nt < 2; ++nt)
#pragma unroll
          for (int k2 = 0; k2 < 2; ++k2)
            Sc[mk][nt] = __builtin_amdgcn_mfma_f32_16x16x32_bf16(
                kf[mk][k2], qf[nt][k2], Sc[mk][nt], 0, 0, 0);

      // V^T direct from global; issued here so softmax hides the latency
      short8 vf[4];
#pragma unroll
      for (int mh = 0; mh < 4; ++mh)
        vf[mh] = *(const short8*)(vtb + (size_t)(mh * 16 + l16) * MROWS
                                  + b * TT + s0 + quad * 8);

      // mask mode: 2 = diagonal (s<=t), 1 = first tile (s>=t-WIN), 0 = none
      const int mode = (s0 == t0) ? 2 : ((t0 >= WIN && s0 == t0 - WIN) ? 1 : 0);

#pragma unroll
      for (int nt = 0; nt < 2; ++nt) {
        const int t = t0 + nt * 16 + l16;
        float p[8], ps = 0.f;
#pragma unroll
        for (int mk = 0; mk < 2; ++mk)
#pragma unroll
          for (int r = 0; r < 4; ++r) {
            float v = Sc[mk][nt][r];
            if (mode) {
              const int s = s0 + mk * 16 + quad * 4 + r;
              const bool kill = (mode == 2) ? (s > t) : (s + WIN < t);
              if (kill) v = -1.0e5f;               // exp2 -> 0
            }
            const float e = fast_exp2(v);
            p[mk * 4 + r] = e; ps += e;
          }
        lq[nt] += ps;                              // reduce over quads at end
        uint2 w0 = make_uint2(pk_bf16_trunc(p[0], p[1]), pk_bf16_trunc(p[2], p[3]));
        uint2 w1 = make_uint2(pk_bf16_trunc(p[4], p[5]), pk_bf16_trunc(p[6], p[7]));
        *(uint2*)(Psb + (nt * 16 + l16) * 40 + quad * 4)      = w0;
        *(uint2*)(Psb + (nt * 16 + l16) * 40 + 16 + quad * 4) = w1;
      }

      // O^T += V^T * P^T  (Ps per-wave: same-wave lgkmcnt ordering)
      short8 pf0 = *(const short8*)(Psb + l16 * 40 + quad * 8);
      short8 pf1 = *(const short8*)(Psb + (16 + l16) * 40 + quad * 8);
#pragma unroll
      for (int mh = 0; mh < 4; ++mh) {
        Oacc[mh][0] = __builtin_amdgcn_mfma_f32_16x16x32_bf16(vf[mh], pf0, Oacc[mh][0], 0, 0, 0);
        Oacc[mh][1] = __builtin_amdgcn_mfma_f32_16x16x32_bf16(vf[mh], pf1, Oacc[mh][1], 0, 0, 0);
      }
    }
    __syncthreads();                        // reads done before next staging
  }

  // ---- sequential 4-way merge in LDS (g1->g0, g3->g2, g2->g0) ----
  // Row per (wh, lane): 36 floats: 32 O + lq0 + lq1 + pad. 36864 B <= 60 KB.
  float* row = (float*)smem + ((size_t)wh * 64 + lane) * 36;

  if (g == 1) {
#pragma unroll
    for (int mh = 0; mh < 4; ++mh)
#pragma unroll
      for (int nt = 0; nt < 2; ++nt)
        *(floatx4*)(row + mh * 8 + nt * 4) = Oacc[mh][nt];
    row[32] = lq[0]; row[33] = lq[1];
  }
  __syncthreads();
  if (g == 0) {
#pragma unroll
    for (int mh = 0; mh < 4; ++mh)
#pragma unroll
      for (int nt = 0; nt < 2; ++nt) {
        floatx4 o1 = *(const floatx4*)(row + mh * 8 + nt * 4);
        Oacc[mh][nt] += o1;
      }
    lq[0] += row[32]; lq[1] += row[33];
  }
  __syncthreads();
  if (g == 3) {
#pragma unroll
    for (int mh = 0; mh < 4; ++mh)
#pragma unroll
      for (int nt = 0; nt < 2; ++nt)
        *(floatx4*)(row + mh * 8 + nt * 4) = Oacc[mh][nt];
    row[32] = lq[0]; row[33] = lq[1];
  }
  __syncthreads();
  if (g == 2) {
#pragma unroll
    for (int mh = 0; mh < 4; ++mh)
#pragma unroll
      for (int nt = 0; nt < 2; ++nt) {
        floatx4 o1 = *(const floatx4*)(row + mh * 8 + nt * 4);
        Oacc[mh][nt] += o1;
      }
    lq[0] += row[32]; lq[1] += row[33];
  }
  __syncthreads();
  if (g == 2) {
#pragma unroll
    for (int mh = 0; mh < 4; ++mh)
#pragma unroll
      for (int nt = 0; nt < 2; ++nt)
        *(floatx4*)(row + mh * 8 + nt * 4) = Oacc[mh][nt];
    row[32] = lq[0]; row[33] = lq[1];
  }
  __syncthreads();
  if (g == 0) {
#pragma unroll
    for (int mh = 0; mh < 4; ++mh)
#pragma unroll
      for (int nt = 0; nt < 2; ++nt) {
        floatx4 o1 = *(const floatx4*)(row + mh * 8 + nt * 4);
        Oacc[mh][nt] += o1;
      }
    lq[0] += row[32]; lq[1] += row[33];
    // deferred quad reduction, then normalize + store
    lq[0] += __shfl_xor(lq[0], 16); lq[0] += __shfl_xor(lq[0], 32);
    lq[1] += __shfl_xor(lq[1], 16); lq[1] += __shfl_xor(lq[1], 32);
#pragma unroll
    for (int nt = 0; nt < 2; ++nt) {
      const float inv = 1.f / lq[nt];
      unsigned short* op = attnb + (size_t)(b * TT + t0 + nt * 16 + l16) * WID
                         + h * HD + quad * 4;
#pragma unroll
      for (int mh = 0; mh < 4; ++mh) {
        ushort4 o4 = make_ushort4(f2bf(Oacc[mh][nt][0] * inv),
                                  f2bf(Oacc[mh][nt][1] * inv),
                                  f2bf(Oacc[mh][nt][2] * inv),
                                  f2bf(Oacc[mh][nt][3] * inv));
        *(ushort4*)(op + mh * 16) = o4;
      }
    }
  }
}

// ---------------------------------------------------------------------------
// Launch: convert -> QKV gemm (bf16 q/k/vT epilogue) -> attention -> out gemm
// ---------------------------------------------------------------------------
extern "C" void kernel_launch(void* const* d_in, const int* in_sizes, int n_in,
                              void* d_out, int out_size, void* d_ws, size_t ws_size,
                              hipStream_t stream) {
  const float* x   = (const float*)d_in[0];
  const float* wq  = (const float*)d_in[2];
  const float* wk  = (const float*)d_in[3];
  const float* wv  = (const float*)d_in[4];
  const float* wf  = (const float*)d_in[5];
  const float* bfp = (const float*)d_in[6];
  float* out = (float*)d_out;

  char* ws = (char*)d_ws;
  unsigned short* xb   = (unsigned short*)(ws + 0);          //  8,388,608
  unsigned short* wb   = (unsigned short*)(ws + 8388608);    //  2,359,296
  unsigned short* wfb  = (unsigned short*)(ws + 10747904);   //  2,097,152
  unsigned short* qbuf = (unsigned short*)(ws + 12845056);   //  8,388,608
  unsigned short* kbuf = (unsigned short*)(ws + 21233664);   //    524,288
  unsigned short* vtb  = (unsigned short*)(ws + 21757952);   //    524,288
  unsigned short* attnb = xb;   // xb dead after QKV gemm -> reuse
  // total 22,282,240 bytes

  hipLaunchKernelGGL(convert_kernel, dim3(1024), dim3(256), 0, stream,
                     x, wq, wk, wv, wf, xb, wb, wfb);
  hipLaunchKernelGGL(gemm64, dim3(MROWS / 64, NQKV / 128), dim3(256), 0, stream,
                     xb, wb, MROWS, NQKV, WID, 1,
                     (float*)nullptr, (const float*)nullptr, qbuf, kbuf, vtb);
  hipLaunchKernelGGL(attn_mfma, dim3(TT / 32, NH / 4, BB), dim3(1024), 0, stream,
                     qbuf, kbuf, vtb, attnb);
  hipLaunchKernelGGL(gemm64, dim3(MROWS / 64, WID / 128), dim3(256), 0, stream,
                     attnb, wfb, MROWS, WID, WID, 0,
                     out, bfp, (unsigned short*)nullptr, (unsigned short*)nullptr,
                     (unsigned short*)nullptr);
}

// Round 9
// 172.512 us; speedup vs baseline: 1.9731x; 1.9731x over previous
//
#include <hip/hip_runtime.h>
#include <cstdint>
#include <cstddef>

// Problem constants
#define BB      2
#define TT      2048
#define WID     1024
#define NH      16
#define HD      64
#define WIN     1024
#define MROWS   (BB*TT)      // 4096
#define NQKV    1152         // 1024 q + 64 k + 64 v
#define QSCL    0.18033688011112042f   // (1/8) * log2(e)  -> exp2-domain logits

typedef __attribute__((ext_vector_type(8))) short  short8;   // 8 bf16 in 4 VGPRs
typedef __attribute__((ext_vector_type(4))) float  floatx4;  // MFMA accumulator

__device__ __forceinline__ unsigned short f2bf(float f) {
  union { float f; unsigned int u; } v; v.f = f;
  unsigned int u = v.u;
  unsigned int r = (u + 0x7fffu + ((u >> 16) & 1u)) >> 16;  // RNE
  return (unsigned short)r;
}

__device__ __forceinline__ float fast_exp2(float x) {
#if __has_builtin(__builtin_amdgcn_exp2f)
  return __builtin_amdgcn_exp2f(x);
#else
  return exp2f(x);
#endif
}

// pack two fp32 -> two bf16 (truncation) in one v_perm_b32
__device__ __forceinline__ unsigned int pk_bf16_trunc(float lo, float hi) {
  union { float f; unsigned int u; } a, b; a.f = lo; b.f = hi;
#if __has_builtin(__builtin_amdgcn_perm)
  return __builtin_amdgcn_perm(b.u, a.u, 0x07060302u);
#else
  return (b.u & 0xffff0000u) | (a.u >> 16);
#endif
}

// async global->LDS, 16B per lane; lds ptr must be wave-uniform (HW adds lane*16)
__device__ __forceinline__ void gld_lds16(const void* g, void* l) {
  __builtin_amdgcn_global_load_lds(
      (const __attribute__((address_space(1))) unsigned int*)g,
      (__attribute__((address_space(3))) unsigned int*)l, 16, 0, 0);
}

// ---------------------------------------------------------------------------
// Kernel 1: fp32 -> bf16 conversion for x, packed W=[Wq;Wk;Wv], Wf
// ---------------------------------------------------------------------------
__global__ __launch_bounds__(256) void convert_kernel(
    const float* __restrict__ x,  const float* __restrict__ wq,
    const float* __restrict__ wk, const float* __restrict__ wv,
    const float* __restrict__ wf,
    unsigned short* __restrict__ xb, unsigned short* __restrict__ wb,
    unsigned short* __restrict__ wfb)
{
  const int NX4 = (MROWS * WID) / 4;
  const int NQ4 = (WID * WID) / 4;
  const int NK4 = (HD * WID) / 4;
  const int NW4 = NQ4 + 2 * NK4;
  const int NF4 = (WID * WID) / 4;
  const int TOT = NX4 + NW4 + NF4;
  for (int i = blockIdx.x * blockDim.x + threadIdx.x; i < TOT;
       i += gridDim.x * blockDim.x) {
    float4 v4;
    unsigned short* dptr;
    if (i < NX4) {
      v4 = ((const float4*)x)[i];
      dptr = xb + (size_t)i * 4;
    } else if (i < NX4 + NW4) {
      int k = i - NX4;
      dptr = wb + (size_t)k * 4;
      if (k < NQ4)            v4 = ((const float4*)wq)[k];
      else if (k < NQ4 + NK4) v4 = ((const float4*)wk)[k - NQ4];
      else                    v4 = ((const float4*)wv)[k - NQ4 - NK4];
    } else {
      int k = i - NX4 - NW4;
      v4 = ((const float4*)wf)[k];
      dptr = wfb + (size_t)k * 4;
    }
    ushort4 o4 = make_ushort4(f2bf(v4.x), f2bf(v4.y), f2bf(v4.z), f2bf(v4.w));
    *(ushort4*)dptr = o4;
  }
}

// ---------------------------------------------------------------------------
// Kernel 2: bf16 MFMA GEMM with split-K=2: P[part](MxN f32) = A_slice*B_slice^T
// BM=64, BN=128, BK=64, 256 threads = 4 waves (2x2), wave = 32x64 out.
// blockIdx.z = part selects K half; partials go to P + part*M*N (f32 stores).
// Staging/swizzle identical to the verified R6 kernel.
// ---------------------------------------------------------------------------
__global__ __launch_bounds__(256) void gemm64s(
    const unsigned short* __restrict__ A, const unsigned short* __restrict__ Bm,
    float* __restrict__ P, int M, int N, int K)
{
  __shared__ __align__(16) unsigned short As[2][64 * 64];    // 2 x 8 KB
  __shared__ __align__(16) unsigned short Bs[2][128 * 64];   // 2 x 16 KB

  const int tid  = threadIdx.x;
  const int m0   = blockIdx.x * 64;
  const int n0   = blockIdx.y * 128;
  const int part = blockIdx.z;
  const int Ks   = K >> 1;              // K-slice length
  const int kb0  = part * Ks;           // slice base
  const int w    = tid >> 6;
  const int lane = tid & 63;
  const int wr   = w >> 1;        // 0..1 -> 32-row slab
  const int wc   = w & 1;         // 0..1 -> 64-col slab
  const int quad = lane >> 4;
  const int l16  = lane & 15;

  const int rS  = tid >> 3;             // 0..31
  const int cS  = tid & 7;
  const int csS = (cS + rS) & 7;
  const unsigned short* gA0 = A  + (size_t)(m0 + rS) * K + kb0 + csS * 8;
  const unsigned short* gA1 = gA0 + (size_t)32 * K;
  const unsigned short* gB0 = Bm + (size_t)(n0 + rS) * K + kb0 + csS * 8;
  const unsigned short* gB1 = gB0 + (size_t)32 * K;
  const unsigned short* gB2 = gB0 + (size_t)64 * K;
  const unsigned short* gB3 = gB0 + (size_t)96 * K;
  const int wub = (tid & 192) * 16;     // wave-uniform byte base within round

  floatx4 acc[2][4];
#pragma unroll
  for (int it = 0; it < 2; ++it)
#pragma unroll
    for (int jt = 0; jt < 4; ++jt)
      acc[it][jt] = (floatx4){0.f, 0.f, 0.f, 0.f};

  const int K64 = Ks >> 6;
  gld_lds16(gA0, (char*)As[0] + wub);
  gld_lds16(gA1, (char*)As[0] + 4096 + wub);
  gld_lds16(gB0, (char*)Bs[0] + wub);
  gld_lds16(gB1, (char*)Bs[0] + 4096 + wub);
  gld_lds16(gB2, (char*)Bs[0] + 8192 + wub);
  gld_lds16(gB3, (char*)Bs[0] + 12288 + wub);
  __syncthreads();

  for (int kt = 0; kt < K64; ++kt) {
    const int cur = kt & 1;
    if (kt + 1 < K64) {
      const int nxt = cur ^ 1;
      const int off = (kt + 1) * 64;
      gld_lds16(gA0 + off, (char*)As[nxt] + wub);
      gld_lds16(gA1 + off, (char*)As[nxt] + 4096 + wub);
      gld_lds16(gB0 + off, (char*)Bs[nxt] + wub);
      gld_lds16(gB1 + off, (char*)Bs[nxt] + 4096 + wub);
      gld_lds16(gB2 + off, (char*)Bs[nxt] + 8192 + wub);
      gld_lds16(gB3 + off, (char*)Bs[nxt] + 12288 + wub);
    }
    const unsigned short* as = As[cur];
    const unsigned short* bs = Bs[cur];
    short8 af[2][2], bfr[4][2];
#pragma unroll
    for (int it = 0; it < 2; ++it) {
      const int m = wr * 32 + it * 16 + l16;
#pragma unroll
      for (int ks = 0; ks < 2; ++ks)
        af[it][ks] = *(const short8*)(as + m * 64 + (((ks * 4 + quad) - m) & 7) * 8);
    }
#pragma unroll
    for (int jt = 0; jt < 4; ++jt) {
      const int n = wc * 64 + jt * 16 + l16;
#pragma unroll
      for (int ks = 0; ks < 2; ++ks)
        bfr[jt][ks] = *(const short8*)(bs + n * 64 + (((ks * 4 + quad) - n) & 7) * 8);
    }
#pragma unroll
    for (int ks = 0; ks < 2; ++ks)
#pragma unroll
      for (int it = 0; it < 2; ++it)
#pragma unroll
        for (int jt = 0; jt < 4; ++jt)
          acc[it][jt] = __builtin_amdgcn_mfma_f32_16x16x32_bf16(
              af[it][ks], bfr[jt][ks], acc[it][jt], 0, 0, 0);
    __syncthreads();
  }

  float* Pp = P + (size_t)part * M * N;
#pragma unroll
  for (int it = 0; it < 2; ++it) {
    const int gr = m0 + wr * 32 + it * 16 + quad * 4;
#pragma unroll
    for (int jt = 0; jt < 4; ++jt) {
      const int gc = n0 + wc * 64 + jt * 16 + l16;
#pragma unroll
      for (int r = 0; r < 4; ++r)
        Pp[(size_t)(gr + r) * N + gc] = acc[it][jt][r];
    }
  }
}

// ---------------------------------------------------------------------------
// Kernel 2b: combine QKV partials -> qb (scaled bf16), kb (bf16), vtb (bf16^T)
// ---------------------------------------------------------------------------
__global__ __launch_bounds__(256) void combine_qkv(
    const float* __restrict__ P, unsigned short* __restrict__ qb,
    unsigned short* __restrict__ kb, unsigned short* __restrict__ vtb)
{
  const float* P0 = P;
  const float* P1 = P + (size_t)MROWS * NQKV;
  const int NQ4 = MROWS * WID / 4;   // 1,048,576
  const int NK4 = MROWS * HD / 4;    //    65,536
  const int NV  = HD * (MROWS / 4);  //    65,536
  const int TOT = NQ4 + NK4 + NV;
  for (int i = blockIdx.x * blockDim.x + threadIdx.x; i < TOT;
       i += gridDim.x * blockDim.x) {
    if (i < NQ4) {
      const int row = i >> 8;
      const int c   = (i & 255) << 2;
      const float4 a = *(const float4*)(P0 + (size_t)row * NQKV + c);
      const float4 b = *(const float4*)(P1 + (size_t)row * NQKV + c);
      ushort4 o = make_ushort4(f2bf((a.x + b.x) * QSCL), f2bf((a.y + b.y) * QSCL),
                               f2bf((a.z + b.z) * QSCL), f2bf((a.w + b.w) * QSCL));
      *(ushort4*)(qb + (size_t)row * WID + c) = o;
    } else if (i < NQ4 + NK4) {
      const int j   = i - NQ4;
      const int row = j >> 4;
      const int c   = (j & 15) << 2;
      const float4 a = *(const float4*)(P0 + (size_t)row * NQKV + WID + c);
      const float4 b = *(const float4*)(P1 + (size_t)row * NQKV + WID + c);
      ushort4 o = make_ushort4(f2bf(a.x + b.x), f2bf(a.y + b.y),
                               f2bf(a.z + b.z), f2bf(a.w + b.w));
      *(ushort4*)(kb + (size_t)row * HD + c) = o;
    } else {
      const int j  = i - NQ4 - NK4;
      const int hd = j >> 10;
      const int r4 = (j & 1023) << 2;
      const int col = WID + HD + hd;
      ushort4 o;
      o.x = f2bf(P0[(size_t)(r4 + 0) * NQKV + col] + P1[(size_t)(r4 + 0) * NQKV + col]);
      o.y = f2bf(P0[(size_t)(r4 + 1) * NQKV + col] + P1[(size_t)(r4 + 1) * NQKV + col]);
      o.z = f2bf(P0[(size_t)(r4 + 2) * NQKV + col] + P1[(size_t)(r4 + 2) * NQKV + col]);
      o.w = f2bf(P0[(size_t)(r4 + 3) * NQKV + col] + P1[(size_t)(r4 + 3) * NQKV + col]);
      *(ushort4*)(vtb + (size_t)hd * MROWS + r4) = o;
    }
  }
}

// ---------------------------------------------------------------------------
// Kernel 2c: combine output partials + bias -> d_out (f32)
// ---------------------------------------------------------------------------
__global__ __launch_bounds__(256) void combine_out(
    const float* __restrict__ P, const float* __restrict__ bias,
    float* __restrict__ out)
{
  const float* P0 = P;
  const float* P1 = P + (size_t)MROWS * WID;
  const int TOT = MROWS * WID / 4;   // 1,048,576
  for (int i = blockIdx.x * blockDim.x + threadIdx.x; i < TOT;
       i += gridDim.x * blockDim.x) {
    const int c = (i & 255) << 2;
    const float4 a  = ((const float4*)P0)[i];
    const float4 b  = ((const float4*)P1)[i];
    const float4 bs = *(const float4*)(bias + c);
    float4 o;
    o.x = a.x + b.x + bs.x; o.y = a.y + b.y + bs.y;
    o.z = a.z + b.z + bs.z; o.w = a.w + b.w + bs.w;
    ((float4*)out)[i] = o;
  }
}

// ---------------------------------------------------------------------------
// Kernel 3: MFMA flash attention (MQA, window=1024) — R6 version, verbatim.
// 512 threads = 8 waves = 4 heads x 2 window-halves; K/V LDS double-buffered,
// ONE barrier/iter; no-max softmax (fixed m=0, exp2 domain); merge in LDS.
// ---------------------------------------------------------------------------
__global__ __launch_bounds__(512) void attn_mfma(
    const unsigned short* __restrict__ qb, const unsigned short* __restrict__ kb,
    const unsigned short* __restrict__ vtb, unsigned short* __restrict__ attnb)
{
  __shared__ __align__(16) unsigned short smem[30720];   // 60 KB

  const int tid  = threadIdx.x;
  const int w    = tid >> 6;        // 0..7
  const int g    = w >> 2;          // window-half group
  const int wh   = w & 3;           // head sub-index
  const int lane = tid & 63;
  const int l16  = lane & 15;
  const int quad = lane >> 4;
  const int t0   = blockIdx.x * 32;
  const int h    = blockIdx.y * 4 + wh;
  const int b    = blockIdx.z;

  unsigned short* Psb = smem + 20480 + w * 1280;    // [query*40 + key]

  short8 qf[2][2];
#pragma unroll
  for (int nt = 0; nt < 2; ++nt) {
    const unsigned short* qp =
        qb + (size_t)(b * TT + t0 + nt * 16 + l16) * WID + h * HD + quad * 8;
    qf[nt][0] = *(const short8*)qp;
    qf[nt][1] = *(const short8*)(qp + 32);
  }

  floatx4 Oacc[4][2];
#pragma unroll
  for (int mh = 0; mh < 4; ++mh)
#pragma unroll
    for (int nt = 0; nt < 2; ++nt)
      Oacc[mh][nt] = (floatx4){0.f, 0.f, 0.f, 0.f};
  float lq[2] = {0.f, 0.f};

  int s_begin = t0 - WIN; if (s_begin < 0) s_begin = 0;
  const int T = ((t0 + 32) - s_begin) >> 5;
  const int I = (T + 1) >> 1;

  const int kkey  = tid >> 3;
  const int khseg = (tid & 7) * 8;
  const int ksel  = kkey >> 5, krow = kkey & 31;
  const int vhd   = tid >> 3;
  const int vkk   = (tid & 7) * 8;
  const int vsel  = vkk >> 5,  vcol = vkk & 31;

  const unsigned short* kbase = kb  + (size_t)(b * TT) * HD;
  const unsigned short* vbase = vtb + (size_t)vhd * MROWS + b * TT;

  int s0p = s_begin;
  int ck = s0p + kkey; if (ck > TT - 1) ck = TT - 1;
  int cv = s0p + vkk;  if (cv > TT - 8) cv = TT - 8;
  short8 kreg = *(const short8*)(kbase + (size_t)ck * HD + khseg);
  short8 vreg = *(const short8*)(vbase + cv);

  for (int i = 0; i < I; ++i) {
    const int buf = i & 1;
    *(short8*)(smem + buf * 5120 + ksel * 2560 + krow * 80 + khseg) = kreg;
    *(short8*)(smem + 10240 + buf * 5120 + vsel * 2560 + vhd * 40 + vcol) = vreg;
    __syncthreads();
    if (i + 1 < I) {
      s0p += 64;
      ck = s0p + kkey; if (ck > TT - 1) ck = TT - 1;
      cv = s0p + vkk;  if (cv > TT - 8) cv = TT - 8;
      kreg = *(const short8*)(kbase + (size_t)ck * HD + khseg);
      vreg = *(const short8*)(vbase + cv);
    }

    const int ta = 2 * i + g;
    if (ta < T) {
      const int s0 = s_begin + ta * 32;
      const unsigned short* ks = smem + buf * 5120 + g * 2560;
      const unsigned short* vs = smem + 10240 + buf * 5120 + g * 2560;

      short8 kf[2][2];
#pragma unroll
      for (int mk = 0; mk < 2; ++mk)
#pragma unroll
        for (int k2 = 0; k2 < 2; ++k2)
          kf[mk][k2] = *(const short8*)(ks + (mk * 16 + l16) * 80 + k2 * 32 + quad * 8);

      floatx4 Sc[2][2];
#pragma unroll
      for (int mk = 0; mk < 2; ++mk)
#pragma unroll
        for (int nt = 0; nt < 2; ++nt)
          Sc[mk][nt] = (floatx4){0.f, 0.f, 0.f, 0.f};
#pragma unroll
      for (int mk = 0; mk < 2; ++mk)
#pragma unroll
        for (int nt = 0; nt < 2; ++nt)
#pragma unroll
          for (int k2 = 0; k2 < 2; ++k2)
            Sc[mk][nt] = __builtin_amdgcn_mfma_f32_16x16x32_bf16(
                kf[mk][k2], qf[nt][k2], Sc[mk][nt], 0, 0, 0);

      const int mode = (s0 == t0) ? 2 : ((t0 >= WIN && s0 == t0 - WIN) ? 1 : 0);

#pragma unroll
      for (int nt = 0; nt < 2; ++nt) {
        const int t = t0 + nt * 16 + l16;
        float p[8], ps = 0.f;
#pragma unroll
        for (int mk = 0; mk < 2; ++mk)
#pragma unroll
          for (int r = 0; r < 4; ++r) {
            float v = Sc[mk][nt][r];
            if (mode) {
              const int s = s0 + mk * 16 + quad * 4 + r;
              const bool kill = (mode == 2) ? (s > t) : (s + WIN < t);
              if (kill) v = -1.0e5f;
            }
            const float e = fast_exp2(v);
            p[mk * 4 + r] = e; ps += e;
          }
        lq[nt] += ps;
        uint2 w0 = make_uint2(pk_bf16_trunc(p[0], p[1]), pk_bf16_trunc(p[2], p[3]));
        uint2 w1 = make_uint2(pk_bf16_trunc(p[4], p[5]), pk_bf16_trunc(p[6], p[7]));
        *(uint2*)(Psb + (nt * 16 + l16) * 40 + quad * 4)      = w0;
        *(uint2*)(Psb + (nt * 16 + l16) * 40 + 16 + quad * 4) = w1;
      }

      short8 pf0 = *(const short8*)(Psb + l16 * 40 + quad * 8);
      short8 pf1 = *(const short8*)(Psb + (16 + l16) * 40 + quad * 8);
#pragma unroll
      for (int mh = 0; mh < 4; ++mh) {
        short8 vf = *(const short8*)(vs + (mh * 16 + l16) * 40 + quad * 8);
        Oacc[mh][0] = __builtin_amdgcn_mfma_f32_16x16x32_bf16(vf, pf0, Oacc[mh][0], 0, 0, 0);
        Oacc[mh][1] = __builtin_amdgcn_mfma_f32_16x16x32_bf16(vf, pf1, Oacc[mh][1], 0, 0, 0);
      }
    }
  }

  lq[0] += __shfl_xor(lq[0], 16); lq[0] += __shfl_xor(lq[0], 32);
  lq[1] += __shfl_xor(lq[1], 16); lq[1] += __shfl_xor(lq[1], 32);

  __syncthreads();
  float* mrg = (float*)smem;
  float* ob  = mrg + wh * 2336 + lane * 36;
  if (g == 1) {
#pragma unroll
    for (int mh = 0; mh < 4; ++mh)
#pragma unroll
      for (int nt = 0; nt < 2; ++nt)
        *(floatx4*)(ob + mh * 8 + nt * 4) = Oacc[mh][nt];
    if (quad == 0) {
      mrg[wh * 2336 + 2304 + l16]      = lq[0];
      mrg[wh * 2336 + 2304 + 16 + l16] = lq[1];
    }
  }
  __syncthreads();
  if (g == 0) {
    lq[0] += mrg[wh * 2336 + 2304 + l16];
    lq[1] += mrg[wh * 2336 + 2304 + 16 + l16];
#pragma unroll
    for (int nt = 0; nt < 2; ++nt) {
      const float inv = 1.f / lq[nt];
      unsigned short* op = attnb + (size_t)(b * TT + t0 + nt * 16 + l16) * WID
                         + h * HD + quad * 4;
#pragma unroll
      for (int mh = 0; mh < 4; ++mh) {
        floatx4 o1 = *(const floatx4*)(ob + mh * 8 + nt * 4);
        ushort4 o4 = make_ushort4(f2bf((Oacc[mh][nt][0] + o1[0]) * inv),
                                  f2bf((Oacc[mh][nt][1] + o1[1]) * inv),
                                  f2bf((Oacc[mh][nt][2] + o1[2]) * inv),
                                  f2bf((Oacc[mh][nt][3] + o1[3]) * inv));
        *(ushort4*)(op + mh * 16) = o4;
      }
    }
  }
}

// ---------------------------------------------------------------------------
// Launch: convert -> QKV gemm (split-K) -> combine_qkv -> attention
//         -> out gemm (split-K) -> combine_out
// ---------------------------------------------------------------------------
extern "C" void kernel_launch(void* const* d_in, const int* in_sizes, int n_in,
                              void* d_out, int out_size, void* d_ws, size_t ws_size,
                              hipStream_t stream) {
  const float* x   = (const float*)d_in[0];
  const float* wq  = (const float*)d_in[2];
  const float* wk  = (const float*)d_in[3];
  const float* wv  = (const float*)d_in[4];
  const float* wf  = (const float*)d_in[5];
  const float* bfp = (const float*)d_in[6];
  float* out = (float*)d_out;

  char* ws = (char*)d_ws;
  unsigned short* xb   = (unsigned short*)(ws + 0);          //  8,388,608
  unsigned short* wb   = (unsigned short*)(ws + 8388608);    //  2,359,296
  unsigned short* wfb  = (unsigned short*)(ws + 10747904);   //  2,097,152
  unsigned short* qbuf = (unsigned short*)(ws + 12845056);   //  8,388,608
  unsigned short* kbuf = (unsigned short*)(ws + 21233664);   //    524,288
  unsigned short* vtb  = (unsigned short*)(ws + 21757952);   //    524,288
  float*          pbuf = (float*)(ws + 22282240);            // 37,748,736 (2x QKV f32; reused for 2x out f32)
  unsigned short* attnb = xb;   // xb dead after QKV gemm -> reuse
  // total 60,030,976 bytes (ws is ~256 MB per fill counter)

  hipLaunchKernelGGL(convert_kernel, dim3(1024), dim3(256), 0, stream,
                     x, wq, wk, wv, wf, xb, wb, wfb);
  hipLaunchKernelGGL(gemm64s, dim3(MROWS / 64, NQKV / 128, 2), dim3(256), 0, stream,
                     xb, wb, pbuf, MROWS, NQKV, WID);
  hipLaunchKernelGGL(combine_qkv, dim3(2048), dim3(256), 0, stream,
                     pbuf, qbuf, kbuf, vtb);
  hipLaunchKernelGGL(attn_mfma, dim3(TT / 32, NH / 4, BB), dim3(512), 0, stream,
                     qbuf, kbuf, vtb, attnb);
  hipLaunchKernelGGL(gemm64s, dim3(MROWS / 64, WID / 128, 2), dim3(256), 0, stream,
                     attnb, wfb, pbuf, MROWS, WID, WID);
  hipLaunchKernelGGL(combine_out, dim3(2048), dim3(256), 0, stream,
                     pbuf, bfp, out);
}

// Round 10
// 161.430 us; speedup vs baseline: 2.1086x; 1.0687x over previous
//
#include <hip/hip_runtime.h>
#include <cstdint>
#include <cstddef>

// Problem constants
#define BB      2
#define TT      2048
#define WID     1024
#define NH      16
#define HD      64
#define WIN     1024
#define MROWS   (BB*TT)      // 4096
#define NQKV    1152         // 1024 q + 64 k + 64 v
#define QSCL    0.18033688011112042f   // (1/8) * log2(e)  -> exp2-domain logits

typedef __attribute__((ext_vector_type(8))) short  short8;   // 8 bf16 in 4 VGPRs
typedef __attribute__((ext_vector_type(4))) float  floatx4;  // MFMA accumulator

__device__ __forceinline__ unsigned short f2bf(float f) {
  union { float f; unsigned int u; } v; v.f = f;
  unsigned int u = v.u;
  unsigned int r = (u + 0x7fffu + ((u >> 16) & 1u)) >> 16;  // RNE
  return (unsigned short)r;
}

__device__ __forceinline__ float fast_exp2(float x) {
#if __has_builtin(__builtin_amdgcn_exp2f)
  return __builtin_amdgcn_exp2f(x);
#else
  return exp2f(x);
#endif
}

// pack two fp32 -> two bf16 (truncation) in one v_perm_b32
__device__ __forceinline__ unsigned int pk_bf16_trunc(float lo, float hi) {
  union { float f; unsigned int u; } a, b; a.f = lo; b.f = hi;
#if __has_builtin(__builtin_amdgcn_perm)
  return __builtin_amdgcn_perm(b.u, a.u, 0x07060302u);
#else
  return (b.u & 0xffff0000u) | (a.u >> 16);
#endif
}

// async global->LDS, 16B per lane; lds ptr must be wave-uniform (HW adds lane*16)
__device__ __forceinline__ void gld_lds16(const void* g, void* l) {
  __builtin_amdgcn_global_load_lds(
      (const __attribute__((address_space(1))) unsigned int*)g,
      (__attribute__((address_space(3))) unsigned int*)l, 16, 0, 0);
}

// ---------------------------------------------------------------------------
// Kernel 1: fp32 -> bf16 conversion for x, packed W=[Wq;Wk;Wv], Wf
// ---------------------------------------------------------------------------
__global__ __launch_bounds__(256) void convert_kernel(
    const float* __restrict__ x,  const float* __restrict__ wq,
    const float* __restrict__ wk, const float* __restrict__ wv,
    const float* __restrict__ wf,
    unsigned short* __restrict__ xb, unsigned short* __restrict__ wb,
    unsigned short* __restrict__ wfb)
{
  const int NX4 = (MROWS * WID) / 4;
  const int NQ4 = (WID * WID) / 4;
  const int NK4 = (HD * WID) / 4;
  const int NW4 = NQ4 + 2 * NK4;
  const int NF4 = (WID * WID) / 4;
  const int TOT = NX4 + NW4 + NF4;
  for (int i = blockIdx.x * blockDim.x + threadIdx.x; i < TOT;
       i += gridDim.x * blockDim.x) {
    float4 v4;
    unsigned short* dptr;
    if (i < NX4) {
      v4 = ((const float4*)x)[i];
      dptr = xb + (size_t)i * 4;
    } else if (i < NX4 + NW4) {
      int k = i - NX4;
      dptr = wb + (size_t)k * 4;
      if (k < NQ4)            v4 = ((const float4*)wq)[k];
      else if (k < NQ4 + NK4) v4 = ((const float4*)wk)[k - NQ4];
      else                    v4 = ((const float4*)wv)[k - NQ4 - NK4];
    } else {
      int k = i - NX4 - NW4;
      v4 = ((const float4*)wf)[k];
      dptr = wfb + (size_t)k * 4;
    }
    ushort4 o4 = make_ushort4(f2bf(v4.x), f2bf(v4.y), f2bf(v4.z), f2bf(v4.w));
    *(ushort4*)dptr = o4;
  }
}

// ---------------------------------------------------------------------------
// Kernel 2: bf16 MFMA GEMM, C(MxN) = A(MxK) * B(NxK)^T.   (R6 version, frozen)
// BM=64, BN=128, BK=64, 256 threads = 4 waves (2x2), wave = 32x64 out,
// 16 MFMA per wave per barrier; double-buffered LDS, ONE barrier per K-iter.
// global_load_lds staging with chunk swizzle (c+row)&7; reader de-swizzles
// with slot (j - m)&7.
// mode 0: C f32 + bias.  mode 1: split bf16 epilogue -> qb (scaled), kb, vtb.
// ---------------------------------------------------------------------------
__global__ __launch_bounds__(256) void gemm64(
    const unsigned short* __restrict__ A, const unsigned short* __restrict__ Bm,
    int M, int N, int K, int mode,
    float* __restrict__ C, const float* __restrict__ bias,
    unsigned short* __restrict__ qb, unsigned short* __restrict__ kb,
    unsigned short* __restrict__ vtb)
{
  __shared__ __align__(16) unsigned short As[2][64 * 64];    // 2 x 8 KB
  __shared__ __align__(16) unsigned short Bs[2][128 * 64];   // 2 x 16 KB

  const int tid  = threadIdx.x;
  const int m0   = blockIdx.x * 64;
  const int n0   = blockIdx.y * 128;
  const int w    = tid >> 6;
  const int lane = tid & 63;
  const int wr   = w >> 1;        // 0..1 -> 32-row slab
  const int wc   = w & 1;         // 0..1 -> 64-col slab
  const int quad = lane >> 4;
  const int l16  = lane & 15;

  const int rS  = tid >> 3;             // 0..31
  const int cS  = tid & 7;
  const int csS = (cS + rS) & 7;
  const unsigned short* gA0 = A  + (size_t)(m0 + rS) * K + csS * 8;
  const unsigned short* gA1 = gA0 + (size_t)32 * K;
  const unsigned short* gB0 = Bm + (size_t)(n0 + rS) * K + csS * 8;
  const unsigned short* gB1 = gB0 + (size_t)32 * K;
  const unsigned short* gB2 = gB0 + (size_t)64 * K;
  const unsigned short* gB3 = gB0 + (size_t)96 * K;
  const int wub = (tid & 192) * 16;     // wave-uniform byte base within round

  floatx4 acc[2][4];
#pragma unroll
  for (int it = 0; it < 2; ++it)
#pragma unroll
    for (int jt = 0; jt < 4; ++jt)
      acc[it][jt] = (floatx4){0.f, 0.f, 0.f, 0.f};

  const int K64 = K >> 6;
  gld_lds16(gA0, (char*)As[0] + wub);
  gld_lds16(gA1, (char*)As[0] + 4096 + wub);
  gld_lds16(gB0, (char*)Bs[0] + wub);
  gld_lds16(gB1, (char*)Bs[0] + 4096 + wub);
  gld_lds16(gB2, (char*)Bs[0] + 8192 + wub);
  gld_lds16(gB3, (char*)Bs[0] + 12288 + wub);
  __syncthreads();

  for (int kt = 0; kt < K64; ++kt) {
    const int cur = kt & 1;
    if (kt + 1 < K64) {
      const int nxt = cur ^ 1;
      const int off = (kt + 1) * 64;
      gld_lds16(gA0 + off, (char*)As[nxt] + wub);
      gld_lds16(gA1 + off, (char*)As[nxt] + 4096 + wub);
      gld_lds16(gB0 + off, (char*)Bs[nxt] + wub);
      gld_lds16(gB1 + off, (char*)Bs[nxt] + 4096 + wub);
      gld_lds16(gB2 + off, (char*)Bs[nxt] + 8192 + wub);
      gld_lds16(gB3 + off, (char*)Bs[nxt] + 12288 + wub);
    }
    const unsigned short* as = As[cur];
    const unsigned short* bs = Bs[cur];
    short8 af[2][2], bfr[4][2];
#pragma unroll
    for (int it = 0; it < 2; ++it) {
      const int m = wr * 32 + it * 16 + l16;
#pragma unroll
      for (int ks = 0; ks < 2; ++ks)
        af[it][ks] = *(const short8*)(as + m * 64 + (((ks * 4 + quad) - m) & 7) * 8);
    }
#pragma unroll
    for (int jt = 0; jt < 4; ++jt) {
      const int n = wc * 64 + jt * 16 + l16;
#pragma unroll
      for (int ks = 0; ks < 2; ++ks)
        bfr[jt][ks] = *(const short8*)(bs + n * 64 + (((ks * 4 + quad) - n) & 7) * 8);
    }
#pragma unroll
    for (int ks = 0; ks < 2; ++ks)
#pragma unroll
      for (int it = 0; it < 2; ++it)
#pragma unroll
        for (int jt = 0; jt < 4; ++jt)
          acc[it][jt] = __builtin_amdgcn_mfma_f32_16x16x32_bf16(
              af[it][ks], bfr[jt][ks], acc[it][jt], 0, 0, 0);
    __syncthreads();
  }

  if (mode == 0) {
#pragma unroll
    for (int it = 0; it < 2; ++it) {
      const int gr = m0 + wr * 32 + it * 16 + quad * 4;
#pragma unroll
      for (int jt = 0; jt < 4; ++jt) {
        const int gc = n0 + wc * 64 + jt * 16 + l16;
        const float badd = bias[gc];
#pragma unroll
        for (int r = 0; r < 4; ++r)
          C[(size_t)(gr + r) * N + gc] = acc[it][jt][r] + badd;
      }
    }
  } else {
#pragma unroll
    for (int it = 0; it < 2; ++it) {
      const int gr = m0 + wr * 32 + it * 16 + quad * 4;
#pragma unroll
      for (int jt = 0; jt < 4; ++jt) {
        const int gc = n0 + wc * 64 + jt * 16 + l16;
        if (gc < WID) {                       // Q columns: scaled bf16
#pragma unroll
          for (int r = 0; r < 4; ++r)
            qb[(size_t)(gr + r) * WID + gc] = f2bf(acc[it][jt][r] * QSCL);
        } else if (gc < WID + HD) {           // K columns
#pragma unroll
          for (int r = 0; r < 4; ++r)
            kb[(size_t)(gr + r) * HD + (gc - WID)] = f2bf(acc[it][jt][r]);
        } else {                              // V columns -> vtb[hd][row]
          ushort4 o4 = make_ushort4(f2bf(acc[it][jt][0]), f2bf(acc[it][jt][1]),
                                    f2bf(acc[it][jt][2]), f2bf(acc[it][jt][3]));
          *(ushort4*)(vtb + (size_t)(gc - WID - HD) * MROWS + gr) = o4;
        }
      }
    }
  }
}

// ---------------------------------------------------------------------------
// Kernel 3: MFMA flash attention (MQA, window=1024) v3 — small blocks for
// occupancy. 256 threads = 4 waves = 2 heads x 2 window-groups; grid
// (64, 8, 2) = 1024 blocks -> 4 blocks/CU (16 waves/CU). K staged in LDS
// (double-buffered, stride 72 = 2-way/free banks, ONE barrier/iter); V^T read
// DIRECT from global (R7-validated: latency hides behind S-MFMA+softmax).
// No-max softmax (fixed m=0, exp2 domain); per-wave P LDS round-trip;
// 2-way merge in LDS at the end. LDS 28.7 KB; launch_bounds(256,4) caps
// VGPR at 128 (R7 body compiled at 64 — no spill expected).
// ---------------------------------------------------------------------------
__global__ __launch_bounds__(256, 4) void attn_mfma(
    const unsigned short* __restrict__ qb, const unsigned short* __restrict__ kb,
    const unsigned short* __restrict__ vtb, unsigned short* __restrict__ attnb)
{
  // shorts: Ks[2 buf][2 tile][32*72] = 9216, Ps[4 waves][32*40] = 5120
  // -> 14336 shorts = 28672 B. Merge epilogue reuses region as float (18 KB).
  __shared__ __align__(16) unsigned short smem[14336];

  const int tid  = threadIdx.x;
  const int w    = tid >> 6;        // 0..3
  const int g    = w >> 1;          // window group (tile parity)
  const int wh   = w & 1;           // head sub-index
  const int lane = tid & 63;
  const int l16  = lane & 15;
  const int quad = lane >> 4;
  const int t0   = blockIdx.x * 32;
  const int h    = blockIdx.y * 2 + wh;
  const int b    = blockIdx.z;

  unsigned short* Psb = smem + 9216 + w * 1280;   // per-wave [query*40 + key]

  // Q B-fragments (pre-scaled bf16): lane=query l16 (+nt*16), k=quad*8+j
  short8 qf[2][2];
#pragma unroll
  for (int nt = 0; nt < 2; ++nt) {
    const unsigned short* qp =
        qb + (size_t)(b * TT + t0 + nt * 16 + l16) * WID + h * HD + quad * 8;
    qf[nt][0] = *(const short8*)qp;
    qf[nt][1] = *(const short8*)(qp + 32);
  }

  floatx4 Oacc[4][2];
#pragma unroll
  for (int mh = 0; mh < 4; ++mh)
#pragma unroll
    for (int nt = 0; nt < 2; ++nt)
      Oacc[mh][nt] = (floatx4){0.f, 0.f, 0.f, 0.f};
  float lq[2] = {0.f, 0.f};                 // per-lane partial sums

  int s_begin = t0 - WIN; if (s_begin < 0) s_begin = 0;
  const int T = ((t0 + 32) - s_begin) >> 5;   // real 32-key tiles (<=33)
  const int I = (T + 1) >> 1;                 // 64-key staging rounds

  // K staging: 512 slots (64 keys x 8 hd-segs); thread handles slots tid,tid+256
  // slot s -> key = s>>3 (0..63), hseg = (s&7)*8 shorts
  const int key0 = tid >> 3,          hs0 = (tid & 7) * 8;
  const int key1 = (tid + 256) >> 3,  hs1 = hs0;           // same (s&7)
  const unsigned short* kbase = kb + (size_t)(b * TT) * HD;

  int sr = s_begin;
  int c0 = sr + key0; if (c0 > TT - 1) c0 = TT - 1;   // OOB clamp (phantom)
  int c1 = sr + key1; if (c1 > TT - 1) c1 = TT - 1;
  short8 kreg0 = *(const short8*)(kbase + (size_t)c0 * HD + hs0);
  short8 kreg1 = *(const short8*)(kbase + (size_t)c1 * HD + hs1);

  for (int i = 0; i < I; ++i) {
    const int buf = i & 1;
    unsigned short* kd = smem + buf * 4608;
    *(short8*)(kd + (key0 >> 5) * 2304 + (key0 & 31) * 72 + hs0) = kreg0;
    *(short8*)(kd + (key1 >> 5) * 2304 + (key1 & 31) * 72 + hs1) = kreg1;
    __syncthreads();
    if (i + 1 < I) {                         // prefetch next 64-key round
      sr += 64;
      c0 = sr + key0; if (c0 > TT - 1) c0 = TT - 1;
      c1 = sr + key1; if (c1 > TT - 1) c1 = TT - 1;
      kreg0 = *(const short8*)(kbase + (size_t)c0 * HD + hs0);
      kreg1 = *(const short8*)(kbase + (size_t)c1 * HD + hs1);
    }

    const int ta = 2 * i + g;
    if (ta < T) {                            // wave-uniform guard
      const int s0 = s_begin + ta * 32;
      const unsigned short* ks = smem + buf * 4608 + g * 2304;

      short8 kf[2][2];
#pragma unroll
      for (int mk = 0; mk < 2; ++mk)
#pragma unroll
        for (int k2 = 0; k2 < 2; ++k2)
          kf[mk][k2] = *(const short8*)(ks + (mk * 16 + l16) * 72 + k2 * 32 + quad * 8);

      floatx4 Sc[2][2];
#pragma unroll
      for (int mk = 0; mk < 2; ++mk)
#pragma unroll
        for (int nt = 0; nt < 2; ++nt)
          Sc[mk][nt] = (floatx4){0.f, 0.f, 0.f, 0.f};
#pragma unroll
      for (int mk = 0; mk < 2; ++mk)
#pragma unroll
        for (int nt = 0; nt < 2; ++nt)
#pragma unroll
          for (int k2 = 0; k2 < 2; ++k2)
            Sc[mk][nt] = __builtin_amdgcn_mfma_f32_16x16x32_bf16(
                kf[mk][k2], qf[nt][k2], Sc[mk][nt], 0, 0, 0);

      // V^T direct from global; issued here so softmax hides the latency
      short8 vf[4];
#pragma unroll
      for (int mh = 0; mh < 4; ++mh)
        vf[mh] = *(const short8*)(vtb + (size_t)(mh * 16 + l16) * MROWS
                                  + b * TT + s0 + quad * 8);

      // mask mode: 2 = diagonal (s<=t), 1 = first tile (s>=t-WIN), 0 = none
      const int mode = (s0 == t0) ? 2 : ((t0 >= WIN && s0 == t0 - WIN) ? 1 : 0);

#pragma unroll
      for (int nt = 0; nt < 2; ++nt) {
        const int t = t0 + nt * 16 + l16;
        float p[8], ps = 0.f;
#pragma unroll
        for (int mk = 0; mk < 2; ++mk)
#pragma unroll
          for (int r = 0; r < 4; ++r) {
            float v = Sc[mk][nt][r];
            if (mode) {
              const int s = s0 + mk * 16 + quad * 4 + r;
              const bool kill = (mode == 2) ? (s > t) : (s + WIN < t);
              if (kill) v = -1.0e5f;               // exp2 -> 0
            }
            const float e = fast_exp2(v);
            p[mk * 4 + r] = e; ps += e;
          }
        lq[nt] += ps;                              // reduce over quads at end
        uint2 w0 = make_uint2(pk_bf16_trunc(p[0], p[1]), pk_bf16_trunc(p[2], p[3]));
        uint2 w1 = make_uint2(pk_bf16_trunc(p[4], p[5]), pk_bf16_trunc(p[6], p[7]));
        *(uint2*)(Psb + (nt * 16 + l16) * 40 + quad * 4)      = w0;
        *(uint2*)(Psb + (nt * 16 + l16) * 40 + 16 + quad * 4) = w1;
      }

      // O^T += V^T * P^T  (Ps per-wave: same-wave lgkmcnt ordering)
      short8 pf0 = *(const short8*)(Psb + l16 * 40 + quad * 8);
      short8 pf1 = *(const short8*)(Psb + (16 + l16) * 40 + quad * 8);
#pragma unroll
      for (int mh = 0; mh < 4; ++mh) {
        Oacc[mh][0] = __builtin_amdgcn_mfma_f32_16x16x32_bf16(vf[mh], pf0, Oacc[mh][0], 0, 0, 0);
        Oacc[mh][1] = __builtin_amdgcn_mfma_f32_16x16x32_bf16(vf[mh], pf1, Oacc[mh][1], 0, 0, 0);
      }
    }
  }

  // reduce deferred l-sums over the quad groups (query = l16 in every quad)
  lq[0] += __shfl_xor(lq[0], 16); lq[0] += __shfl_xor(lq[0], 32);
  lq[1] += __shfl_xor(lq[1], 16); lq[1] += __shfl_xor(lq[1], 32);

  // merge the two window-halves (pure add; no max state). Scratch overlaps
  // Ks/Ps -> barrier before writes and before reads.
  __syncthreads();
  float* mrg = (float*)smem;
  float* ob  = mrg + ((size_t)wh * 64 + lane) * 36;  // 36 fl = 144 B, 16B-aligned
  if (g == 1) {
#pragma unroll
    for (int mh = 0; mh < 4; ++mh)
#pragma unroll
      for (int nt = 0; nt < 2; ++nt)
        *(floatx4*)(ob + mh * 8 + nt * 4) = Oacc[mh][nt];
    ob[32] = lq[0]; ob[33] = lq[1];
  }
  __syncthreads();
  if (g == 0) {
    lq[0] += ob[32]; lq[1] += ob[33];
#pragma unroll
    for (int nt = 0; nt < 2; ++nt) {
      const float inv = 1.f / lq[nt];
      unsigned short* op = attnb + (size_t)(b * TT + t0 + nt * 16 + l16) * WID
                         + h * HD + quad * 4;
#pragma unroll
      for (int mh = 0; mh < 4; ++mh) {
        floatx4 o1 = *(const floatx4*)(ob + mh * 8 + nt * 4);
        ushort4 o4 = make_ushort4(f2bf((Oacc[mh][nt][0] + o1[0]) * inv),
                                  f2bf((Oacc[mh][nt][1] + o1[1]) * inv),
                                  f2bf((Oacc[mh][nt][2] + o1[2]) * inv),
                                  f2bf((Oacc[mh][nt][3] + o1[3]) * inv));
        *(ushort4*)(op + mh * 16) = o4;
      }
    }
  }
}

// ---------------------------------------------------------------------------
// Launch: convert -> QKV gemm (bf16 q/k/vT epilogue) -> attention -> out gemm
// ---------------------------------------------------------------------------
extern "C" void kernel_launch(void* const* d_in, const int* in_sizes, int n_in,
                              void* d_out, int out_size, void* d_ws, size_t ws_size,
                              hipStream_t stream) {
  const float* x   = (const float*)d_in[0];
  const float* wq  = (const float*)d_in[2];
  const float* wk  = (const float*)d_in[3];
  const float* wv  = (const float*)d_in[4];
  const float* wf  = (const float*)d_in[5];
  const float* bfp = (const float*)d_in[6];
  float* out = (float*)d_out;

  char* ws = (char*)d_ws;
  unsigned short* xb   = (unsigned short*)(ws + 0);          //  8,388,608
  unsigned short* wb   = (unsigned short*)(ws + 8388608);    //  2,359,296
  unsigned short* wfb  = (unsigned short*)(ws + 10747904);   //  2,097,152
  unsigned short* qbuf = (unsigned short*)(ws + 12845056);   //  8,388,608
  unsigned short* kbuf = (unsigned short*)(ws + 21233664);   //    524,288
  unsigned short* vtb  = (unsigned short*)(ws + 21757952);   //    524,288
  unsigned short* attnb = xb;   // xb dead after QKV gemm -> reuse
  // total 22,282,240 bytes

  hipLaunchKernelGGL(convert_kernel, dim3(1024), dim3(256), 0, stream,
                     x, wq, wk, wv, wf, xb, wb, wfb);
  hipLaunchKernelGGL(gemm64, dim3(MROWS / 64, NQKV / 128), dim3(256), 0, stream,
                     xb, wb, MROWS, NQKV, WID, 1,
                     (float*)nullptr, (const float*)nullptr, qbuf, kbuf, vtb);
  hipLaunchKernelGGL(attn_mfma, dim3(TT / 32, NH / 2, BB), dim3(256), 0, stream,
                     qbuf, kbuf, vtb, attnb);
  hipLaunchKernelGGL(gemm64, dim3(MROWS / 64, WID / 128), dim3(256), 0, stream,
                     attnb, wfb, MROWS, WID, WID, 0,
                     out, bfp, (unsigned short*)nullptr, (unsigned short*)nullptr,
                     (unsigned short*)nullptr);
}